// Round 9
// baseline (287.788 us; speedup 1.0000x reference)
//
#include <hip/hip_runtime.h>

#define DD 64          // node embedding dim
#define RR 8           // num relations
#define KA 576         // (RR+1)*DD : agg rows 0..7 + x as "relation 8"
#define NT 18          // K steps = KA/32
#define NPART 8        // dst partitions ~ XCDs (blockIdx%8 round-robin)
#define ECH 2048       // edges per slice-block in partitioned kernels

typedef short bf16x8 __attribute__((ext_vector_type(8)));   // 8 bf16
typedef float f32x4  __attribute__((ext_vector_type(4)));

__device__ __forceinline__ float bf2f(unsigned short u) {
    union { unsigned u; float f; } c; c.u = ((unsigned)u) << 16; return c.f;
}
__device__ __forceinline__ unsigned short f2bf(float f) {
    union { float f; unsigned u; } c; c.f = f;
    unsigned u = c.u;
    u += 0x7FFF + ((u >> 16) & 1);      // round-to-nearest-even
    return (unsigned short)(u >> 16);
}

// ---------------------------------------------------------------------------
// x -> bf16 rows; row N is an all-zero pad row (targets of dummy pad edges).
// ---------------------------------------------------------------------------
__global__ void k_xcast(const float* __restrict__ x, unsigned short* __restrict__ xb,
                        int N)
{
    int i = blockIdx.x * 256 + threadIdx.x;              // quad index
    int total = (N + 1) * (DD / 4);
    if (i >= total) return;
    ushort4 o;
    if (i < N * (DD / 4)) {
        float4 f = ((const float4*)x)[i];
        o = make_ushort4(f2bf(f.x), f2bf(f.y), f2bf(f.z), f2bf(f.w));
    } else {
        o = make_ushort4(0, 0, 0, 0);
    }
    ((ushort4*)xb)[i] = o;
}

// ---------------------------------------------------------------------------
// Partitioned count, 8-deep batched: 8 independent dst loads in flight,
// masked et loads, then 8 independent no-return atomics. MLP x8 vs looped.
// ---------------------------------------------------------------------------
__global__ __launch_bounds__(256) void k_count_part(
    const int* __restrict__ ei, const int* __restrict__ et,
    int* __restrict__ cnt, int E, int N)
{
    const int p    = blockIdx.x & (NPART - 1);
    const int sb   = blockIdx.x / NPART;
    const int dlo  = (int)((long long)N * p / NPART);
    const int dhi  = (int)((long long)N * (p + 1) / NPART);
    const int base = sb * ECH + threadIdx.x;

    int d[8]; bool m[8]; int t[8];
    #pragma unroll
    for (int j = 0; j < 8; ++j) {
        int e = base + j * 256;
        d[j] = (e < E) ? ei[E + e] : -1;
    }
    #pragma unroll
    for (int j = 0; j < 8; ++j) m[j] = (d[j] >= dlo && d[j] < dhi);
    #pragma unroll
    for (int j = 0; j < 8; ++j) {
        int e = base + j * 256;
        if (m[j]) t[j] = et[e];
    }
    #pragma unroll
    for (int j = 0; j < 8; ++j)
        if (m[j]) atomicAdd(&cnt[(size_t)d[j] * RR + t[j]], 1);
}

// ---------------------------------------------------------------------------
// Per-dst bucket allocation (padded to x8) + per-(dst,rel) cell heads, so
// the bucket scatter produces rel-ORDERED runs inside each dst bucket.
// Pad entries (src=N -> zero row) sit after run 7.
// ---------------------------------------------------------------------------
__global__ __launch_bounds__(256) void k_alloc(
    const int* __restrict__ cnt, int* __restrict__ startv,
    int* __restrict__ head2, int* __restrict__ counter,
    int* __restrict__ sorted, int N)
{
    __shared__ int sdata[256];
    __shared__ int sbase;
    const int tid = threadIdx.x;
    const int n = blockIdx.x * 256 + tid;

    int deg = 0, deg8 = 0;
    int c[RR];
    if (n < N) {
        const int4* c4 = (const int4*)(cnt + (size_t)n * RR);
        int4 a = c4[0], b = c4[1];
        c[0]=a.x; c[1]=a.y; c[2]=a.z; c[3]=a.w;
        c[4]=b.x; c[5]=b.y; c[6]=b.z; c[7]=b.w;
        #pragma unroll
        for (int r = 0; r < RR; ++r) deg += c[r];
        deg8 = (deg + 7) & ~7;
    }
    sdata[tid] = deg8;
    __syncthreads();
    int v = deg8;
    #pragma unroll
    for (int off = 1; off < 256; off <<= 1) {
        int t = (tid >= off) ? sdata[tid - off] : 0;
        __syncthreads();
        v += t;
        sdata[tid] = v;
        __syncthreads();
    }
    if (tid == 255) sbase = atomicAdd(counter, v);
    __syncthreads();
    if (n < N) {
        int st = sbase + v - deg8;
        startv[n] = st;
        int h = st;
        #pragma unroll
        for (int r = 0; r < RR; ++r) { head2[(size_t)n * RR + r] = h; h += c[r]; }
        for (int j = deg; j < deg8; ++j) sorted[st + j] = N;   // pad -> zero row
    }
}

// ---------------------------------------------------------------------------
// Partitioned bucket scatter into rel-ordered runs, 8-deep batched:
// 8 dst loads -> masks -> masked et/src loads -> 8 INDEPENDENT returning
// atomics in flight -> 8 dependent stores. sorted[pos] = src.
// ---------------------------------------------------------------------------
__global__ __launch_bounds__(256) void k_bucket_part(
    const int* __restrict__ ei, const int* __restrict__ et,
    int* __restrict__ head2, int* __restrict__ sorted, int E, int N)
{
    const int p    = blockIdx.x & (NPART - 1);
    const int sb   = blockIdx.x / NPART;
    const int dlo  = (int)((long long)N * p / NPART);
    const int dhi  = (int)((long long)N * (p + 1) / NPART);
    const int base = sb * ECH + threadIdx.x;

    int d[8]; bool m[8]; int t[8], s[8], pos[8];
    #pragma unroll
    for (int j = 0; j < 8; ++j) {
        int e = base + j * 256;
        d[j] = (e < E) ? ei[E + e] : -1;
    }
    #pragma unroll
    for (int j = 0; j < 8; ++j) m[j] = (d[j] >= dlo && d[j] < dhi);
    #pragma unroll
    for (int j = 0; j < 8; ++j) {
        int e = base + j * 256;
        if (m[j]) { t[j] = et[e]; s[j] = ei[e]; }
    }
    #pragma unroll
    for (int j = 0; j < 8; ++j)
        if (m[j]) pos[j] = atomicAdd(&head2[(size_t)d[j] * RR + t[j]], 1);
    #pragma unroll
    for (int j = 0; j < 8; ++j)
        if (m[j]) sorted[pos[j]] = s[j];
}

// ---------------------------------------------------------------------------
// Pack Wcat = [W_rel(8) ; W_root] into MFMA-B fragment order (bf16 hi only;
// absmax headroom is ~4 orders of magnitude, lo-pass dropped).
// ---------------------------------------------------------------------------
__global__ void k_packW(const float* __restrict__ Wrel, const float* __restrict__ Wroot,
                        unsigned short* __restrict__ Bh)
{
    int idx = blockIdx.x * 256 + threadIdx.x;
    if (idx >= NT * 4 * 64 * 8) return;
    int i    = idx & 7;
    int lane = (idx >> 3) & 63;
    int f    = (idx >> 9) & 3;
    int t    = idx >> 11;
    int k = t * 32 + (lane >> 4) * 8 + i;
    int d = f * 16 + (lane & 15);
    int r = k >> 6, kk = k & 63;
    float w = (r < RR) ? Wrel[((size_t)r * DD + kk) * DD + d]
                       : Wroot[(size_t)kk * DD + d];
    Bh[idx] = f2bf(w);
}

// ---------------------------------------------------------------------------
// One wave per dst. Bucket is rel-ordered + padded to x8: flat 8-wide
// pipelined gather into a SINGLE accumulator; at run boundaries (wave-uniform
// scalars) flush cur*rcp(cnt) to the agg row. ~3 VALU/edge, no routing.
// ---------------------------------------------------------------------------
__global__ __launch_bounds__(256) void k_aggregate(
    const unsigned short* __restrict__ xb, const int* __restrict__ sorted,
    const int* __restrict__ startv, const int* __restrict__ cnt,
    unsigned short* __restrict__ agg, int c0, int c1)
{
    const int wv   = threadIdx.x >> 6;
    const int lane = threadIdx.x & 63;
    const int dst  = c0 + blockIdx.x * 4 + wv;
    if (dst >= c1) return;

    // lane r (r = lane&7) holds cnt[dst*8+r]; scalars extracted via readlane
    const int cv = cnt[(size_t)dst * RR + (lane & 7)];
    int deg = 0;
    #pragma unroll
    for (int r = 0; r < RR; ++r) deg += __builtin_amdgcn_readlane(cv, r);
    const int deg8 = (deg + 7) & ~7;

    const int s0  = __builtin_amdgcn_readfirstlane(startv[dst]);
    const int end = s0 + deg8;

    unsigned short* ao = agg + (size_t)(dst - c0) * KA + lane;

    // run-flush state (wave-uniform)
    int   r      = 0;
    int   c_r    = __builtin_amdgcn_readlane(cv, 0);
    int   next_b = s0 + c_r;
    float cur    = 0.f;

    auto flush = [&]() {
        float inv = __builtin_amdgcn_rcpf(fmaxf((float)c_r, 1.f));
        ao[r * DD] = f2bf(cur * inv);
        cur = 0.f;
        ++r;
        c_r = __builtin_amdgcn_readlane(cv, r & 7);
        next_b += c_r;
    };

    int e = s0;
    int wbase = s0;
    int vidx  = sorted[wbase + lane];
    while (e < end) {
        if (e - wbase >= 64) {                 // slide 64-edge index window
            wbase = e;
            vidx  = sorted[wbase + lane];
        }
        const int k    = e - wbase;            // uniform, multiple of 8
        const int take = min(end - e, 64 - k); // multiple of 8
        for (int i = 0; i < take; i += 8) {
            int q0 = __builtin_amdgcn_readlane(vidx, k + i + 0);
            int q1 = __builtin_amdgcn_readlane(vidx, k + i + 1);
            int q2 = __builtin_amdgcn_readlane(vidx, k + i + 2);
            int q3 = __builtin_amdgcn_readlane(vidx, k + i + 3);
            int q4 = __builtin_amdgcn_readlane(vidx, k + i + 4);
            int q5 = __builtin_amdgcn_readlane(vidx, k + i + 5);
            int q6 = __builtin_amdgcn_readlane(vidx, k + i + 6);
            int q7 = __builtin_amdgcn_readlane(vidx, k + i + 7);
            unsigned short u0 = xb[(size_t)q0 * DD + lane];   // 8 loads in flight
            unsigned short u1 = xb[(size_t)q1 * DD + lane];
            unsigned short u2 = xb[(size_t)q2 * DD + lane];
            unsigned short u3 = xb[(size_t)q3 * DD + lane];
            unsigned short u4 = xb[(size_t)q4 * DD + lane];
            unsigned short u5 = xb[(size_t)q5 * DD + lane];
            unsigned short u6 = xb[(size_t)q6 * DD + lane];
            unsigned short u7 = xb[(size_t)q7 * DD + lane];
            const int base = e + i;
            while (base + 0 == next_b && r < RR) flush();
            cur += bf2f(u0);
            while (base + 1 == next_b && r < RR) flush();
            cur += bf2f(u1);
            while (base + 2 == next_b && r < RR) flush();
            cur += bf2f(u2);
            while (base + 3 == next_b && r < RR) flush();
            cur += bf2f(u3);
            while (base + 4 == next_b && r < RR) flush();
            cur += bf2f(u4);
            while (base + 5 == next_b && r < RR) flush();
            cur += bf2f(u5);
            while (base + 6 == next_b && r < RR) flush();
            cur += bf2f(u6);
            while (base + 7 == next_b && r < RR) flush();
            cur += bf2f(u7);
        }
        e += take;
    }
    while (r < RR) flush();                    // drain (covers empties, deg=0)

    ao[8 * DD] = xb[(size_t)dst * DD + lane];  // x row, already bf16
}

// ---------------------------------------------------------------------------
// out[64-node tile] = A(64x576) @ Bh(576x64) + bias   via MFMA bf16.
// ---------------------------------------------------------------------------
__global__ __launch_bounds__(256) void k_transform_mfma(
    const unsigned short* __restrict__ A,
    const unsigned short* __restrict__ Bh,
    const float* __restrict__ bias,
    float* __restrict__ out, int c0, int c1)
{
    const int nb   = c0 + blockIdx.x * 64;
    const int wv   = threadIdx.x >> 6;
    const int lane = threadIdx.x & 63;
    const int rlo  = lane & 15;        // A row within 16 / D col within 16
    const int kg   = lane >> 4;        // k-group

    const unsigned short* ap = A + ((size_t)(nb - c0) + wv * 16 + rlo) * KA + kg * 8;

    f32x4 acc0 = {0.f,0.f,0.f,0.f};
    f32x4 acc1 = {0.f,0.f,0.f,0.f};
    f32x4 acc2 = {0.f,0.f,0.f,0.f};
    f32x4 acc3 = {0.f,0.f,0.f,0.f};

    #pragma unroll
    for (int t = 0; t < NT; ++t) {
        bf16x8 a = *(const bf16x8*)(ap + t * 32);
        const unsigned short* bh = Bh + (size_t)t * 2048 + lane * 8;
        bf16x8 b;
        b = *(const bf16x8*)(bh +    0); acc0 = __builtin_amdgcn_mfma_f32_16x16x32_bf16(a, b, acc0, 0, 0, 0);
        b = *(const bf16x8*)(bh +  512); acc1 = __builtin_amdgcn_mfma_f32_16x16x32_bf16(a, b, acc1, 0, 0, 0);
        b = *(const bf16x8*)(bh + 1024); acc2 = __builtin_amdgcn_mfma_f32_16x16x32_bf16(a, b, acc2, 0, 0, 0);
        b = *(const bf16x8*)(bh + 1536); acc3 = __builtin_amdgcn_mfma_f32_16x16x32_bf16(a, b, acc3, 0, 0, 0);
    }

    // C/D layout: col = lane&15, row = (lane>>4)*4 + reg
    const float b0 = bias[rlo];
    const float b1 = bias[rlo + 16];
    const float b2 = bias[rlo + 32];
    const float b3 = bias[rlo + 48];
    const int orow = nb + wv * 16 + kg * 4;
    #pragma unroll
    for (int j = 0; j < 4; ++j) {
        int rr = orow + j;
        if (rr < c1) {
            float* op = out + (size_t)rr * DD + rlo;
            op[0]  = acc0[j] + b0;
            op[16] = acc1[j] + b1;
            op[32] = acc2[j] + b2;
            op[48] = acc3[j] + b3;
        }
    }
}

// ---------------------------------------------------------------------------
// echo edge_index / edge_type into d_out tail as float
// ---------------------------------------------------------------------------
__global__ void k_echo(const int* __restrict__ ei, const int* __restrict__ et,
                       float* __restrict__ out_ei, float* __restrict__ out_et,
                       int E)
{
    int i = blockIdx.x * 256 + threadIdx.x;
    if (i < 2 * E) out_ei[i] = (float)ei[i];
    if (i < E)     out_et[i] = (float)et[i];
}

extern "C" void kernel_launch(void* const* d_in, const int* in_sizes, int n_in,
                              void* d_out, int out_size, void* d_ws, size_t ws_size,
                              hipStream_t stream)
{
    const float* x     = (const float*)d_in[0];
    const int*   ei    = (const int*)d_in[1];
    const int*   et    = (const int*)d_in[2];
    const float* Wrel  = (const float*)d_in[3];
    const float* Wroot = (const float*)d_in[4];
    const float* bias  = (const float*)d_in[5];

    const int N = in_sizes[0] / DD;
    const int E = in_sizes[2];
    const int M = N * RR;

    float* out    = (float*)d_out;
    float* out_ei = out + (size_t)N * DD;
    float* out_et = out_ei + (size_t)2 * E;

    auto align = [](size_t v) { return (v + 255) & ~(size_t)255; };

    // workspace layout
    size_t p = 0;
    int* cnt = (int*)((char*)d_ws + p);              p += align((size_t)M * 4);
    int* counter = (int*)((char*)d_ws + p);
    size_t zero_bytes = p + 256;                     p += 256;
    int* startv = (int*)((char*)d_ws + p);           p += align((size_t)N * 4);
    int* head2  = (int*)((char*)d_ws + p);           p += align((size_t)M * 4);
    int* sorted = (int*)((char*)d_ws + p);           p += align(((size_t)E + 7*(size_t)N + 128) * 4);
    unsigned short* xb = (unsigned short*)((char*)d_ws + p); p += align(((size_t)N + 1) * DD * 2);
    unsigned short* Bh = (unsigned short*)((char*)d_ws + p); p += align((size_t)NT*4*64*8*2);
    unsigned short* agg = (unsigned short*)((char*)d_ws + p);
    size_t avail = (ws_size > p) ? ws_size - p : 0;

    const size_t per_node = (size_t)KA * 2;          // 1152 B
    int chunk = (int)(((avail / per_node) - 64) & ~(size_t)63);
    if (chunk > N) chunk = (N + 63) & ~(size_t)63;
    if (chunk < 64) chunk = 64;

    hipMemsetAsync(d_ws, 0, zero_bytes, stream);     // cnt + counter

    const int nsb = (E + ECH - 1) / ECH;             // slice-blocks per partition

    k_xcast <<<dim3(((N + 1) * (DD/4) + 255) / 256), 256, 0, stream>>>(x, xb, N);
    k_packW <<<dim3((NT*4*64*8 + 255) / 256), 256, 0, stream>>>(Wrel, Wroot, Bh);
    k_count_part <<<dim3(nsb * NPART), 256, 0, stream>>>(ei, et, cnt, E, N);
    k_alloc <<<dim3((N + 255) / 256), 256, 0, stream>>>(cnt, startv, head2,
                                                        counter, sorted, N);
    k_bucket_part<<<dim3(nsb * NPART), 256, 0, stream>>>(ei, et, head2, sorted, E, N);

    for (int c0 = 0; c0 < N; c0 += chunk) {
        int c1 = min(N, c0 + chunk);
        int nc = c1 - c0;
        k_aggregate     <<<dim3((nc + 3) / 4),   256, 0, stream>>>(
            xb, sorted, startv, cnt, agg, c0, c1);
        k_transform_mfma<<<dim3((nc + 63) / 64), 256, 0, stream>>>(
            agg, Bh, bias, out, c0, c1);
    }

    k_echo<<<dim3((2 * E + 255) / 256), 256, 0, stream>>>(ei, et, out_ei, out_et, E);
}

// Round 10
// 244.357 us; speedup vs baseline: 1.1777x; 1.1777x over previous
//
#include <hip/hip_runtime.h>

#define DD 64          // node embedding dim
#define RR 8           // num relations
#define KA 576         // (RR+1)*DD : agg rows 0..7 + x as "relation 8"
#define NT 18          // K steps = KA/32
#define NPART 8        // dst partitions ~ XCDs (blockIdx%8 round-robin)
#define ECH 2048       // edges per slice-block in partitioned kernels

typedef short bf16x8 __attribute__((ext_vector_type(8)));   // 8 bf16
typedef float f32x4  __attribute__((ext_vector_type(4)));

__device__ __forceinline__ float bf2f(unsigned short u) {
    union { unsigned u; float f; } c; c.u = ((unsigned)u) << 16; return c.f;
}
__device__ __forceinline__ unsigned short f2bf(float f) {
    union { float f; unsigned u; } c; c.f = f;
    unsigned u = c.u;
    u += 0x7FFF + ((u >> 16) & 1);      // round-to-nearest-even
    return (unsigned short)(u >> 16);
}

// ---------------------------------------------------------------------------
// x -> bf16 rows; row N is an all-zero pad row (targets of dummy pad edges).
// ---------------------------------------------------------------------------
__global__ void k_xcast(const float* __restrict__ x, unsigned short* __restrict__ xb,
                        int N)
{
    int i = blockIdx.x * 256 + threadIdx.x;              // quad index
    int total = (N + 1) * (DD / 4);
    if (i >= total) return;
    ushort4 o;
    if (i < N * (DD / 4)) {
        float4 f = ((const float4*)x)[i];
        o = make_ushort4(f2bf(f.x), f2bf(f.y), f2bf(f.z), f2bf(f.w));
    } else {
        o = make_ushort4(0, 0, 0, 0);
    }
    ((ushort4*)xb)[i] = o;
}

// ---------------------------------------------------------------------------
// Count + rank fused (UNpartitioned, full-lane, 8-deep): every thread issues
// 8 independent returning atomics -> real MLP. rank stored as rr = rank|rel<<24
// (rank < E < 2^24). rr written sequentially (clean full-lane stores).
// ---------------------------------------------------------------------------
__global__ __launch_bounds__(256) void k_count_rank(
    const int* __restrict__ ei, const int* __restrict__ et,
    int* __restrict__ cnt, unsigned* __restrict__ rr, int E)
{
    const int base = blockIdx.x * ECH + threadIdx.x;
    int d[8], t[8], rk[8]; bool m[8];
    #pragma unroll
    for (int j = 0; j < 8; ++j) {
        int e = base + j * 256;
        m[j] = (e < E);
        d[j] = m[j] ? ei[E + e] : 0;
    }
    #pragma unroll
    for (int j = 0; j < 8; ++j) {
        int e = base + j * 256;
        if (m[j]) t[j] = et[e];
    }
    #pragma unroll
    for (int j = 0; j < 8; ++j)
        if (m[j]) rk[j] = atomicAdd(&cnt[(size_t)d[j] * RR + t[j]], 1);
    #pragma unroll
    for (int j = 0; j < 8; ++j) {
        int e = base + j * 256;
        if (m[j]) rr[e] = (unsigned)rk[j] | ((unsigned)t[j] << 24);
    }
}

// ---------------------------------------------------------------------------
// Per-dst bucket allocation (padded to x8) + per-(dst,rel) cell starts, so
// scatter can compute positions WITHOUT atomics. Pads (src=N -> zero row)
// written after run 7.
// ---------------------------------------------------------------------------
__global__ __launch_bounds__(256) void k_alloc(
    const int* __restrict__ cnt, int* __restrict__ startv,
    int* __restrict__ start2, int* __restrict__ counter,
    int* __restrict__ sorted, int N)
{
    __shared__ int sdata[256];
    __shared__ int sbase;
    const int tid = threadIdx.x;
    const int n = blockIdx.x * 256 + tid;

    int deg = 0, deg8 = 0;
    int c[RR];
    if (n < N) {
        const int4* c4 = (const int4*)(cnt + (size_t)n * RR);
        int4 a = c4[0], b = c4[1];
        c[0]=a.x; c[1]=a.y; c[2]=a.z; c[3]=a.w;
        c[4]=b.x; c[5]=b.y; c[6]=b.z; c[7]=b.w;
        #pragma unroll
        for (int r = 0; r < RR; ++r) deg += c[r];
        deg8 = (deg + 7) & ~7;
    }
    sdata[tid] = deg8;
    __syncthreads();
    int v = deg8;
    #pragma unroll
    for (int off = 1; off < 256; off <<= 1) {
        int t = (tid >= off) ? sdata[tid - off] : 0;
        __syncthreads();
        v += t;
        sdata[tid] = v;
        __syncthreads();
    }
    if (tid == 255) sbase = atomicAdd(counter, v);
    __syncthreads();
    if (n < N) {
        int st = sbase + v - deg8;
        startv[n] = st;
        int h = st;
        #pragma unroll
        for (int r = 0; r < RR; ++r) { start2[(size_t)n * RR + r] = h; h += c[r]; }
        for (int j = deg; j < deg8; ++j) sorted[st + j] = N;   // pad -> zero row
    }
}

// ---------------------------------------------------------------------------
// Partitioned scatter, NO atomics: pos = start2[cell] + rank (from rr).
// Pure load->store 8-deep pipeline; stores are XCD-local per partition.
// ---------------------------------------------------------------------------
__global__ __launch_bounds__(256) void k_scatter_part(
    const int* __restrict__ ei, const unsigned* __restrict__ rr,
    const int* __restrict__ start2, int* __restrict__ sorted, int E, int N)
{
    const int p    = blockIdx.x & (NPART - 1);
    const int sb   = blockIdx.x / NPART;
    const int dlo  = (int)((long long)N * p / NPART);
    const int dhi  = (int)((long long)N * (p + 1) / NPART);
    const int base = sb * ECH + threadIdx.x;

    int d[8]; bool m[8]; unsigned q[8]; int s[8], st[8];
    #pragma unroll
    for (int j = 0; j < 8; ++j) {
        int e = base + j * 256;
        d[j] = (e < E) ? ei[E + e] : -1;
    }
    #pragma unroll
    for (int j = 0; j < 8; ++j) m[j] = (d[j] >= dlo && d[j] < dhi);
    #pragma unroll
    for (int j = 0; j < 8; ++j) {
        int e = base + j * 256;
        if (m[j]) { q[j] = rr[e]; s[j] = ei[e]; }
    }
    #pragma unroll
    for (int j = 0; j < 8; ++j)
        if (m[j]) st[j] = start2[(size_t)d[j] * RR + (q[j] >> 24)];
    #pragma unroll
    for (int j = 0; j < 8; ++j)
        if (m[j]) sorted[st[j] + (q[j] & 0xFFFFFFu)] = s[j];
}

// ---------------------------------------------------------------------------
// Pack Wcat = [W_rel(8) ; W_root] into MFMA-B fragment order (bf16 hi only;
// absmax headroom is ~4 orders of magnitude, lo-pass dropped).
// ---------------------------------------------------------------------------
__global__ void k_packW(const float* __restrict__ Wrel, const float* __restrict__ Wroot,
                        unsigned short* __restrict__ Bh)
{
    int idx = blockIdx.x * 256 + threadIdx.x;
    if (idx >= NT * 4 * 64 * 8) return;
    int i    = idx & 7;
    int lane = (idx >> 3) & 63;
    int f    = (idx >> 9) & 3;
    int t    = idx >> 11;
    int k = t * 32 + (lane >> 4) * 8 + i;
    int d = f * 16 + (lane & 15);
    int r = k >> 6, kk = k & 63;
    float w = (r < RR) ? Wrel[((size_t)r * DD + kk) * DD + d]
                       : Wroot[(size_t)kk * DD + d];
    Bh[idx] = f2bf(w);
}

// ---------------------------------------------------------------------------
// One wave per dst. Bucket is rel-ordered + padded to x8: flat 8-wide
// pipelined gather into a SINGLE accumulator; at run boundaries (wave-uniform
// scalars) flush cur*rcp(cnt) to the agg row. ~3 VALU/edge, no routing.
// ---------------------------------------------------------------------------
__global__ __launch_bounds__(256) void k_aggregate(
    const unsigned short* __restrict__ xb, const int* __restrict__ sorted,
    const int* __restrict__ startv, const int* __restrict__ cnt,
    unsigned short* __restrict__ agg, int c0, int c1)
{
    const int wv   = threadIdx.x >> 6;
    const int lane = threadIdx.x & 63;
    const int dst  = c0 + blockIdx.x * 4 + wv;
    if (dst >= c1) return;

    // lane r (r = lane&7) holds cnt[dst*8+r]; scalars extracted via readlane
    const int cv = cnt[(size_t)dst * RR + (lane & 7)];
    int deg = 0;
    #pragma unroll
    for (int r = 0; r < RR; ++r) deg += __builtin_amdgcn_readlane(cv, r);
    const int deg8 = (deg + 7) & ~7;

    const int s0  = __builtin_amdgcn_readfirstlane(startv[dst]);
    const int end = s0 + deg8;

    unsigned short* ao = agg + (size_t)(dst - c0) * KA + lane;

    // run-flush state (wave-uniform)
    int   r      = 0;
    int   c_r    = __builtin_amdgcn_readlane(cv, 0);
    int   next_b = s0 + c_r;
    float cur    = 0.f;

    auto flush = [&]() {
        float inv = __builtin_amdgcn_rcpf(fmaxf((float)c_r, 1.f));
        ao[r * DD] = f2bf(cur * inv);
        cur = 0.f;
        ++r;
        c_r = __builtin_amdgcn_readlane(cv, r & 7);
        next_b += c_r;
    };

    int e = s0;
    int wbase = s0;
    int vidx  = sorted[wbase + lane];
    while (e < end) {
        if (e - wbase >= 64) {                 // slide 64-edge index window
            wbase = e;
            vidx  = sorted[wbase + lane];
        }
        const int k    = e - wbase;            // uniform, multiple of 8
        const int take = min(end - e, 64 - k); // multiple of 8
        for (int i = 0; i < take; i += 8) {
            int q0 = __builtin_amdgcn_readlane(vidx, k + i + 0);
            int q1 = __builtin_amdgcn_readlane(vidx, k + i + 1);
            int q2 = __builtin_amdgcn_readlane(vidx, k + i + 2);
            int q3 = __builtin_amdgcn_readlane(vidx, k + i + 3);
            int q4 = __builtin_amdgcn_readlane(vidx, k + i + 4);
            int q5 = __builtin_amdgcn_readlane(vidx, k + i + 5);
            int q6 = __builtin_amdgcn_readlane(vidx, k + i + 6);
            int q7 = __builtin_amdgcn_readlane(vidx, k + i + 7);
            unsigned short u0 = xb[(size_t)q0 * DD + lane];   // 8 loads in flight
            unsigned short u1 = xb[(size_t)q1 * DD + lane];
            unsigned short u2 = xb[(size_t)q2 * DD + lane];
            unsigned short u3 = xb[(size_t)q3 * DD + lane];
            unsigned short u4 = xb[(size_t)q4 * DD + lane];
            unsigned short u5 = xb[(size_t)q5 * DD + lane];
            unsigned short u6 = xb[(size_t)q6 * DD + lane];
            unsigned short u7 = xb[(size_t)q7 * DD + lane];
            const int base = e + i;
            while (base + 0 == next_b && r < RR) flush();
            cur += bf2f(u0);
            while (base + 1 == next_b && r < RR) flush();
            cur += bf2f(u1);
            while (base + 2 == next_b && r < RR) flush();
            cur += bf2f(u2);
            while (base + 3 == next_b && r < RR) flush();
            cur += bf2f(u3);
            while (base + 4 == next_b && r < RR) flush();
            cur += bf2f(u4);
            while (base + 5 == next_b && r < RR) flush();
            cur += bf2f(u5);
            while (base + 6 == next_b && r < RR) flush();
            cur += bf2f(u6);
            while (base + 7 == next_b && r < RR) flush();
            cur += bf2f(u7);
        }
        e += take;
    }
    while (r < RR) flush();                    // drain (covers empties, deg=0)

    ao[8 * DD] = xb[(size_t)dst * DD + lane];  // x row, already bf16
}

// ---------------------------------------------------------------------------
// out[64-node tile] = A(64x576) @ Bh(576x64) + bias   via MFMA bf16.
// ---------------------------------------------------------------------------
__global__ __launch_bounds__(256) void k_transform_mfma(
    const unsigned short* __restrict__ A,
    const unsigned short* __restrict__ Bh,
    const float* __restrict__ bias,
    float* __restrict__ out, int c0, int c1)
{
    const int nb   = c0 + blockIdx.x * 64;
    const int wv   = threadIdx.x >> 6;
    const int lane = threadIdx.x & 63;
    const int rlo  = lane & 15;        // A row within 16 / D col within 16
    const int kg   = lane >> 4;        // k-group

    const unsigned short* ap = A + ((size_t)(nb - c0) + wv * 16 + rlo) * KA + kg * 8;

    f32x4 acc0 = {0.f,0.f,0.f,0.f};
    f32x4 acc1 = {0.f,0.f,0.f,0.f};
    f32x4 acc2 = {0.f,0.f,0.f,0.f};
    f32x4 acc3 = {0.f,0.f,0.f,0.f};

    #pragma unroll
    for (int t = 0; t < NT; ++t) {
        bf16x8 a = *(const bf16x8*)(ap + t * 32);
        const unsigned short* bh = Bh + (size_t)t * 2048 + lane * 8;
        bf16x8 b;
        b = *(const bf16x8*)(bh +    0); acc0 = __builtin_amdgcn_mfma_f32_16x16x32_bf16(a, b, acc0, 0, 0, 0);
        b = *(const bf16x8*)(bh +  512); acc1 = __builtin_amdgcn_mfma_f32_16x16x32_bf16(a, b, acc1, 0, 0, 0);
        b = *(const bf16x8*)(bh + 1024); acc2 = __builtin_amdgcn_mfma_f32_16x16x32_bf16(a, b, acc2, 0, 0, 0);
        b = *(const bf16x8*)(bh + 1536); acc3 = __builtin_amdgcn_mfma_f32_16x16x32_bf16(a, b, acc3, 0, 0, 0);
    }

    // C/D layout: col = lane&15, row = (lane>>4)*4 + reg
    const float b0 = bias[rlo];
    const float b1 = bias[rlo + 16];
    const float b2 = bias[rlo + 32];
    const float b3 = bias[rlo + 48];
    const int orow = nb + wv * 16 + kg * 4;
    #pragma unroll
    for (int j = 0; j < 4; ++j) {
        int rr2 = orow + j;
        if (rr2 < c1) {
            float* op = out + (size_t)rr2 * DD + rlo;
            op[0]  = acc0[j] + b0;
            op[16] = acc1[j] + b1;
            op[32] = acc2[j] + b2;
            op[48] = acc3[j] + b3;
        }
    }
}

// ---------------------------------------------------------------------------
// echo edge_index / edge_type into d_out tail as float
// ---------------------------------------------------------------------------
__global__ void k_echo(const int* __restrict__ ei, const int* __restrict__ et,
                       float* __restrict__ out_ei, float* __restrict__ out_et,
                       int E)
{
    int i = blockIdx.x * 256 + threadIdx.x;
    if (i < 2 * E) out_ei[i] = (float)ei[i];
    if (i < E)     out_et[i] = (float)et[i];
}

extern "C" void kernel_launch(void* const* d_in, const int* in_sizes, int n_in,
                              void* d_out, int out_size, void* d_ws, size_t ws_size,
                              hipStream_t stream)
{
    const float* x     = (const float*)d_in[0];
    const int*   ei    = (const int*)d_in[1];
    const int*   et    = (const int*)d_in[2];
    const float* Wrel  = (const float*)d_in[3];
    const float* Wroot = (const float*)d_in[4];
    const float* bias  = (const float*)d_in[5];

    const int N = in_sizes[0] / DD;
    const int E = in_sizes[2];
    const int M = N * RR;

    float* out    = (float*)d_out;
    float* out_ei = out + (size_t)N * DD;
    float* out_et = out_ei + (size_t)2 * E;

    auto align = [](size_t v) { return (v + 255) & ~(size_t)255; };

    // workspace layout
    size_t p = 0;
    int* cnt = (int*)((char*)d_ws + p);              p += align((size_t)M * 4);
    int* counter = (int*)((char*)d_ws + p);
    size_t zero_bytes = p + 256;                     p += 256;
    int* startv = (int*)((char*)d_ws + p);           p += align((size_t)N * 4);
    int* start2 = (int*)((char*)d_ws + p);           p += align((size_t)M * 4);
    unsigned* rr = (unsigned*)((char*)d_ws + p);     p += align((size_t)E * 4);
    int* sorted = (int*)((char*)d_ws + p);           p += align(((size_t)E + 7*(size_t)N + 128) * 4);
    unsigned short* xb = (unsigned short*)((char*)d_ws + p); p += align(((size_t)N + 1) * DD * 2);
    unsigned short* Bh = (unsigned short*)((char*)d_ws + p); p += align((size_t)NT*4*64*8*2);
    unsigned short* agg = (unsigned short*)((char*)d_ws + p);
    size_t avail = (ws_size > p) ? ws_size - p : 0;

    const size_t per_node = (size_t)KA * 2;          // 1152 B
    int chunk = (int)(((avail / per_node) - 64) & ~(size_t)63);
    if (chunk > N) chunk = (N + 63) & ~(size_t)63;
    if (chunk < 64) chunk = 64;

    hipMemsetAsync(d_ws, 0, zero_bytes, stream);     // cnt + counter

    const int nsb = (E + ECH - 1) / ECH;             // slice-blocks per partition

    k_xcast <<<dim3(((N + 1) * (DD/4) + 255) / 256), 256, 0, stream>>>(x, xb, N);
    k_packW <<<dim3((NT*4*64*8 + 255) / 256), 256, 0, stream>>>(Wrel, Wroot, Bh);
    k_count_rank <<<dim3(nsb), 256, 0, stream>>>(ei, et, cnt, rr, E);
    k_alloc <<<dim3((N + 255) / 256), 256, 0, stream>>>(cnt, startv, start2,
                                                        counter, sorted, N);
    k_scatter_part<<<dim3(nsb * NPART), 256, 0, stream>>>(ei, rr, start2, sorted, E, N);

    for (int c0 = 0; c0 < N; c0 += chunk) {
        int c1 = min(N, c0 + chunk);
        int nc = c1 - c0;
        k_aggregate     <<<dim3((nc + 3) / 4),   256, 0, stream>>>(
            xb, sorted, startv, cnt, agg, c0, c1);
        k_transform_mfma<<<dim3((nc + 63) / 64), 256, 0, stream>>>(
            agg, Bh, bias, out, c0, c1);
    }

    k_echo<<<dim3((2 * E + 255) / 256), 256, 0, stream>>>(ei, et, out_ei, out_et, E);
}